// Round 11
// baseline (957.555 us; speedup 1.0000x reference)
//
#include <hip/hip_runtime.h>

// GCN: 3-layer, N=100000, E=1600000, feat 128->128->128->64, fp32 in/out.
// R11: XCD-sliced aggregation for the two 128-wide layers. T' stored
// slice-major: 8 slices x (N x 16 feats, 32B rows, 3.2MB/slice -- fits one
// XCD's 4MB L2). Agg grid: slice = blockIdx&7 (round-robin block->XCD), so
// each XCD gathers only from its resident slice (L2 hits, not LLC). Slab
// cols re-read per slice with nontemporal loads (no hot-slice pollution).
// dis[] deleted -- consumers compute rsqrtf(deg+1) from slab count.
// 8 dispatches: prep(zero+split) -> edges -> [gemm -> agg] x3.

typedef __attribute__((ext_vector_type(8))) short bf16x8;
typedef __attribute__((ext_vector_type(4))) float floatx4;

#define STRIDE 96  // ints per row slab: 1 count + 95 col slots

// ---------------- helpers ----------------

__device__ inline unsigned short f2bf(float f) {
    union { float f; unsigned u; } v; v.f = f;
    unsigned r = v.u + 0x7fffu + ((v.u >> 16) & 1u);  // RNE
    return (unsigned short)(r >> 16);
}

__device__ inline float bf2f(unsigned short h) {
    union { unsigned u; float f; } v; v.u = (unsigned)h << 16;
    return v.f;
}

__device__ inline void split_bf(float v, unsigned short& h, unsigned short& l) {
    h = f2bf(v);
    l = f2bf(v - bf2f(h));
}

__device__ inline void bf2x_to_f(unsigned u, float& a, float& b) {
    union { unsigned x; float f; } lo, hi;
    lo.x = u << 16; hi.x = u & 0xffff0000u;
    a = lo.f; b = hi.f;
}

__device__ inline void accw8(float* acc, uint4 u, float w) {
    float a, b;
    bf2x_to_f(u.x, a, b); acc[0] = fmaf(w, a, acc[0]); acc[1] = fmaf(w, b, acc[1]);
    bf2x_to_f(u.y, a, b); acc[2] = fmaf(w, a, acc[2]); acc[3] = fmaf(w, b, acc[3]);
    bf2x_to_f(u.z, a, b); acc[4] = fmaf(w, a, acc[4]); acc[5] = fmaf(w, b, acc[5]);
    bf2x_to_f(u.w, a, b); acc[6] = fmaf(w, a, acc[6]); acc[7] = fmaf(w, b, acc[7]);
}

__device__ inline int ntl(const int* p) { return __builtin_nontemporal_load(p); }

// ---------------- slab CSR build (one atomic pass) ----------------

__global__ void k_edges(const int* __restrict__ row, const int* __restrict__ col,
                        int* __restrict__ slab, int e) {
    int base = (blockIdx.x * blockDim.x + threadIdx.x) * 8;
    if (base + 7 < e) {
        int4 r0 = *(const int4*)&row[base];
        int4 r1 = *(const int4*)&row[base + 4];
        int4 c0 = *(const int4*)&col[base];
        int4 c1 = *(const int4*)&col[base + 4];
        int s0 = atomicAdd(&slab[(size_t)r0.x * STRIDE], 1);
        int s1 = atomicAdd(&slab[(size_t)r0.y * STRIDE], 1);
        int s2 = atomicAdd(&slab[(size_t)r0.z * STRIDE], 1);
        int s3 = atomicAdd(&slab[(size_t)r0.w * STRIDE], 1);
        int s4 = atomicAdd(&slab[(size_t)r1.x * STRIDE], 1);
        int s5 = atomicAdd(&slab[(size_t)r1.y * STRIDE], 1);
        int s6 = atomicAdd(&slab[(size_t)r1.z * STRIDE], 1);
        int s7 = atomicAdd(&slab[(size_t)r1.w * STRIDE], 1);
        if (s0 < STRIDE - 1) slab[(size_t)r0.x * STRIDE + 1 + s0] = c0.x;
        if (s1 < STRIDE - 1) slab[(size_t)r0.y * STRIDE + 1 + s1] = c0.y;
        if (s2 < STRIDE - 1) slab[(size_t)r0.z * STRIDE + 1 + s2] = c0.z;
        if (s3 < STRIDE - 1) slab[(size_t)r0.w * STRIDE + 1 + s3] = c0.w;
        if (s4 < STRIDE - 1) slab[(size_t)r1.x * STRIDE + 1 + s4] = c1.x;
        if (s5 < STRIDE - 1) slab[(size_t)r1.y * STRIDE + 1 + s5] = c1.y;
        if (s6 < STRIDE - 1) slab[(size_t)r1.z * STRIDE + 1 + s6] = c1.z;
        if (s7 < STRIDE - 1) slab[(size_t)r1.w * STRIDE + 1 + s7] = c1.w;
    } else {
        for (int k = base; k < e; k++) {
            int r = row[k];
            int s = atomicAdd(&slab[(size_t)r * STRIDE], 1);
            if (s < STRIDE - 1) slab[(size_t)r * STRIDE + 1 + s] = col[k];
        }
    }
}

// ---------------- fused prep: slab zero + X split + W transposes ----------------

__global__ void k_prep(const float* __restrict__ X, unsigned short* __restrict__ Xhi,
                       unsigned short* __restrict__ Xlo,
                       const float* __restrict__ W0, const float* __restrict__ W1,
                       const float* __restrict__ W2,
                       unsigned short* __restrict__ Wt0h, unsigned short* __restrict__ Wt0l,
                       unsigned short* __restrict__ Wt1h, unsigned short* __restrict__ Wt1l,
                       unsigned short* __restrict__ Wt2h, unsigned short* __restrict__ Wt2l,
                       int* __restrict__ slab, int n, int total4) {
    int gid = blockIdx.x * blockDim.x + threadIdx.x;
    int gsz = gridDim.x * blockDim.x;
    for (int i = gid; i < n; i += gsz) slab[(size_t)i * STRIDE] = 0;
    for (int id = gid; id < total4; id += gsz) {
        float4 v = ((const float4*)X)[id];
        ushort4 h, l;
        split_bf(v.x, h.x, l.x);
        split_bf(v.y, h.y, l.y);
        split_bf(v.z, h.z, l.z);
        split_bf(v.w, h.w, l.w);
        ((ushort4*)Xhi)[id] = h;
        ((ushort4*)Xlo)[id] = l;
    }
    for (int id = gid; id < 128 * 128; id += gsz) {
        int k = id >> 7, nn = id & 127;
        unsigned short h, l;
        split_bf(W0[id], h, l);
        Wt0h[nn * 128 + k] = h;
        Wt0l[nn * 128 + k] = l;
        split_bf(W1[id], h, l);
        Wt1h[nn * 128 + k] = h;
        Wt1l[nn * 128 + k] = l;
    }
    for (int id = gid; id < 128 * 64; id += gsz) {
        int k = id >> 6, nn = id & 63;
        unsigned short h, l;
        split_bf(W2[id], h, l);
        Wt2h[nn * 128 + k] = h;
        Wt2l[nn * 128 + k] = l;
    }
}

// ---------------- split-bf16 MFMA GEMM ----------------
// T' = dis[r] * (A @ W). SLICED: write slice-major Ts[s][node][16] (s=gc/16);
// else row-major T[node][LDW]. dis computed from slab count.
// Verified layouts: mfma_f32_16x16x32_bf16, A[m=lane&15][k=quad*8+j],
// C/D col=lane&15 row=quad*4+reg.

template <int NB, bool SLICED>  // LDW = NB*64
__global__ __launch_bounds__(256) void k_gemm_mfma(
    const unsigned short* __restrict__ Ahi, const unsigned short* __restrict__ Alo,
    const unsigned short* __restrict__ Wthi, const unsigned short* __restrict__ Wtlo,
    const int* __restrict__ slab, unsigned short* __restrict__ T, int n) {
    const int LDW = NB * 64;
    __shared__ unsigned short Ah_s[64 * 128];
    __shared__ unsigned short Al_s[64 * 128];
    const int tid = threadIdx.x;
    const int bid = blockIdx.x;
    const int bx = (NB == 2) ? (bid >> 1) : bid;
    const int by = (NB == 2) ? (bid & 1) : 0;
    const int row0 = bx * 64;
    const int col0 = by * 64;

    const int wave = tid >> 6, lane = tid & 63;
    const int ln = lane & 15, quad = lane >> 4;
    const int m0 = (wave >> 1) * 32;
    const int nq0 = (wave & 1) * 32;

    bf16x8 Bh[4][2], Bl[4][2];
#pragma unroll
    for (int s = 0; s < 4; s++)
#pragma unroll
        for (int j = 0; j < 2; j++) {
            int ncol = col0 + nq0 + 16 * j + ln;
            int koff = 32 * s + quad * 8;
            Bh[s][j] = *(const bf16x8*)&Wthi[ncol * 128 + koff];
            Bl[s][j] = *(const bf16x8*)&Wtlo[ncol * 128 + koff];
        }

#pragma unroll
    for (int k = 0; k < 4; k++) {
        int id = k * 256 + tid;
        int r = id >> 4, c = id & 15;
        int gr = row0 + r;
        uint4 vh = make_uint4(0, 0, 0, 0), vl = make_uint4(0, 0, 0, 0);
        if (gr < n) {
            vh = *(const uint4*)&Ahi[(size_t)gr * 128 + c * 8];
            vl = *(const uint4*)&Alo[(size_t)gr * 128 + c * 8];
        }
        int pc = c ^ (r & 15);
        *(uint4*)&Ah_s[r * 128 + pc * 8] = vh;
        *(uint4*)&Al_s[r * 128 + pc * 8] = vl;
    }
    __syncthreads();

    floatx4 acc[2][2];
#pragma unroll
    for (int i = 0; i < 2; i++)
#pragma unroll
        for (int j = 0; j < 2; j++) acc[i][j] = (floatx4){0.f, 0.f, 0.f, 0.f};

#pragma unroll
    for (int s = 0; s < 4; s++) {
        bf16x8 ah[2], al[2];
#pragma unroll
        for (int i = 0; i < 2; i++) {
            int off = (m0 + 16 * i + ln) * 128 + ((4 * s + quad) ^ ln) * 8;
            ah[i] = *(const bf16x8*)&Ah_s[off];
            al[i] = *(const bf16x8*)&Al_s[off];
        }
#pragma unroll
        for (int i = 0; i < 2; i++)
#pragma unroll
            for (int j = 0; j < 2; j++) {
                acc[i][j] = __builtin_amdgcn_mfma_f32_16x16x32_bf16(
                    ah[i], Bh[s][j], acc[i][j], 0, 0, 0);
                acc[i][j] = __builtin_amdgcn_mfma_f32_16x16x32_bf16(
                    ah[i], Bl[s][j], acc[i][j], 0, 0, 0);
                acc[i][j] = __builtin_amdgcn_mfma_f32_16x16x32_bf16(
                    al[i], Bh[s][j], acc[i][j], 0, 0, 0);
            }
    }

#pragma unroll
    for (int i = 0; i < 2; i++)
#pragma unroll
        for (int reg = 0; reg < 4; reg++) {
            int gr = row0 + m0 + 16 * i + quad * 4 + reg;
            if (gr < n) {
                int degt = slab[(size_t)gr * STRIDE];  // broadcast within quad
                float ds = rsqrtf((float)(degt + 1));
#pragma unroll
                for (int j = 0; j < 2; j++) {
                    unsigned short o = f2bf(ds * acc[i][j][reg]);
                    if (SLICED) {
                        int s = ((col0 + nq0) >> 4) + j;
                        T[((size_t)s * n + gr) * 16 + ln] = o;
                    } else {
                        int gc = col0 + nq0 + 16 * j + ln;
                        T[(size_t)gr * LDW + gc] = o;
                    }
                }
            }
        }
}

// ---------------- XCD-sliced aggregation (128-wide layers) ----------------
// slice = blockIdx&7 -> one XCD gathers only its 3.2MB slice (L2-resident).
// Per wave: one node; 8 edge-groups x 8 lanes (uint = 2 feats), unroll x2.
// out = dis*(sum T's[col] + T's[wid]) + bias, relu, emit hi/lo bf16 split.

__global__ __launch_bounds__(256) void k_agg128s(
    const unsigned short* __restrict__ Ts,
    unsigned short* __restrict__ Ohi, unsigned short* __restrict__ Olo,
    const int* __restrict__ slab, const float* __restrict__ bias,
    int n, int npb) {
    const int s = blockIdx.x & 7;
    const int nb0 = (blockIdx.x >> 3) * npb;
    const int wave = threadIdx.x >> 6, lane = threadIdx.x & 63;
    const int g = lane >> 3;   // edge group 0..7
    const int fo = lane & 7;   // feat-pair (2 bf16)
    const unsigned short* Tsl = Ts + (size_t)s * n * 16;
    int nend = nb0 + npb;
    if (nend > n) nend = n;

    for (int wid = nb0 + wave; wid < nend; wid += 4) {
        const int* sl = slab + (size_t)wid * STRIDE;
        int degt = ntl(sl);
        int deg = (degt > STRIDE - 1) ? (STRIDE - 1) : degt;
        float a0 = 0.f, a1 = 0.f;
        int e = g;
        for (; e + 8 < deg; e += 16) {
            int c0 = ntl(&sl[1 + e]);
            int c1 = ntl(&sl[1 + e + 8]);
            unsigned u0 = *(const unsigned*)&Tsl[(size_t)c0 * 16 + fo * 2];
            unsigned u1 = *(const unsigned*)&Tsl[(size_t)c1 * 16 + fo * 2];
            float x, y;
            bf2x_to_f(u0, x, y); a0 += x; a1 += y;
            bf2x_to_f(u1, x, y); a0 += x; a1 += y;
        }
        if (e < deg) {
            int c0 = ntl(&sl[1 + e]);
            unsigned u0 = *(const unsigned*)&Tsl[(size_t)c0 * 16 + fo * 2];
            float x, y;
            bf2x_to_f(u0, x, y); a0 += x; a1 += y;
        }
        // reduce over the 8 edge groups
        a0 += __shfl_xor(a0, 8);  a1 += __shfl_xor(a1, 8);
        a0 += __shfl_xor(a0, 16); a1 += __shfl_xor(a1, 16);
        a0 += __shfl_xor(a0, 32); a1 += __shfl_xor(a1, 32);
        if (g == 0) {
            unsigned us = *(const unsigned*)&Tsl[(size_t)wid * 16 + fo * 2];
            float sx, sy;
            bf2x_to_f(us, sx, sy);
            a0 += sx; a1 += sy;
            float di = rsqrtf((float)(degt + 1));
            float2 bb = *(const float2*)&bias[s * 16 + fo * 2];
            float o0 = fmaxf(fmaf(di, a0, bb.x), 0.f);  // relu
            float o1 = fmaxf(fmaf(di, a1, bb.y), 0.f);
            unsigned short h0, l0, h1, l1;
            split_bf(o0, h0, l0);
            split_bf(o1, h1, l1);
            size_t ob = (size_t)wid * 128 + s * 16 + fo * 2;
            *(unsigned*)&Ohi[ob] = (unsigned)h0 | ((unsigned)h1 << 16);
            *(unsigned*)&Olo[ob] = (unsigned)l0 | ((unsigned)l1 << 16);
        }
    }
}

// ---------------- final aggregation (64-wide, row-major T, fp32 out) ----------

__global__ void k_agg64(const unsigned short* __restrict__ T, float* __restrict__ O,
                        const int* __restrict__ slab, const float* __restrict__ bias,
                        int n) {
    int wid = (blockIdx.x * blockDim.x + threadIdx.x) >> 6;
    int lane = threadIdx.x & 63;
    if (wid >= n) return;
    const int oct = lane >> 3;
    const int fl = (lane & 7) * 8;
    int beg = wid * STRIDE + 1;
    int degt = slab[(size_t)wid * STRIDE];
    int deg = (degt > STRIDE - 1) ? (STRIDE - 1) : degt;
    int end = beg + deg;
    int span = (deg + 7) >> 3;
    int qb = beg + oct * span;
    int qe = qb + span;
    if (qe > end) qe = end;

    float acc[8] = {0.f, 0.f, 0.f, 0.f, 0.f, 0.f, 0.f, 0.f};
    for (int e = qb; e < qe; e += 4) {
        int l = qe - 1;
        int i1 = e + 1, i2 = e + 2, i3 = e + 3;
        int c0 = slab[e];
        int c1 = slab[i1 < l ? i1 : l];
        int c2 = slab[i2 < l ? i2 : l];
        int c3 = slab[i3 < l ? i3 : l];
        float m1 = (i1 < qe) ? 1.f : 0.f;
        float m2 = (i2 < qe) ? 1.f : 0.f;
        float m3 = (i3 < qe) ? 1.f : 0.f;
        uint4 u0 = *(const uint4*)&T[(size_t)c0 * 64 + fl];
        uint4 u1 = *(const uint4*)&T[(size_t)c1 * 64 + fl];
        uint4 u2 = *(const uint4*)&T[(size_t)c2 * 64 + fl];
        uint4 u3 = *(const uint4*)&T[(size_t)c3 * 64 + fl];
        accw8(acc, u0, 1.f);
        accw8(acc, u1, m1);
        accw8(acc, u2, m2);
        accw8(acc, u3, m3);
    }
#pragma unroll
    for (int k = 0; k < 8; k++) {
        acc[k] += __shfl_xor(acc[k], 8);
        acc[k] += __shfl_xor(acc[k], 16);
        acc[k] += __shfl_xor(acc[k], 32);
    }
    if (oct == 0) {
        uint4 us = *(const uint4*)&T[(size_t)wid * 64 + fl];
        accw8(acc, us, 1.f);  // self term
        float di = rsqrtf((float)(degt + 1));
        float4 bA = *(const float4*)&bias[fl];
        float4 bB = *(const float4*)&bias[fl + 4];
        float bb[8] = {bA.x, bA.y, bA.z, bA.w, bB.x, bB.y, bB.z, bB.w};
        float o[8];
#pragma unroll
        for (int k = 0; k < 8; k++)
            o[k] = fmaf(di, acc[k], bb[k]);
        *(float4*)&O[(size_t)wid * 64 + fl] = make_float4(o[0], o[1], o[2], o[3]);
        *(float4*)&O[(size_t)wid * 64 + fl + 4] = make_float4(o[4], o[5], o[6], o[7]);
    }
}

// ---------------- launch ----------------

static inline char* align256(char* p) {
    return (char*)(((uintptr_t)p + 255) & ~(uintptr_t)255);
}

extern "C" void kernel_launch(void* const* d_in, const int* in_sizes, int n_in,
                              void* d_out, int out_size, void* d_ws, size_t ws_size,
                              hipStream_t stream) {
    const float* x  = (const float*)d_in[0];
    const int*   ei = (const int*)d_in[1];
    const float* W0 = (const float*)d_in[2];
    const float* b0 = (const float*)d_in[3];
    const float* W1 = (const float*)d_in[4];
    const float* b1 = (const float*)d_in[5];
    const float* W2 = (const float*)d_in[6];
    const float* b2 = (const float*)d_in[7];

    const int Nn = in_sizes[0] / 128;
    const int Ee = in_sizes[1] / 2;
    const int* rowI = ei;
    const int* colI = ei + Ee;

    char* p = (char*)d_ws;
    unsigned short* Tb  = (unsigned short*)p; p += (size_t)Nn * 128 * 2; p = align256(p);
    unsigned short* Ahi = (unsigned short*)p; p += (size_t)Nn * 128 * 2; p = align256(p);
    unsigned short* Alo = (unsigned short*)p; p += (size_t)Nn * 128 * 2; p = align256(p);
    int* slab   = (int*)p;   p += (size_t)Nn * STRIDE * 4; p = align256(p);
    unsigned short* Wt0h = (unsigned short*)p; p += 128 * 128 * 2;
    unsigned short* Wt0l = (unsigned short*)p; p += 128 * 128 * 2;
    unsigned short* Wt1h = (unsigned short*)p; p += 128 * 128 * 2;
    unsigned short* Wt1l = (unsigned short*)p; p += 128 * 128 * 2;
    unsigned short* Wt2h = (unsigned short*)p; p += 64 * 128 * 2;
    unsigned short* Wt2l = (unsigned short*)p; p += 64 * 128 * 2;

    const int eb8 = (Ee / 8 + 255) / 256;  // 8 edges per thread

    k_prep<<<512, 256, 0, stream>>>(x, Ahi, Alo, W0, W1, W2,
                                    Wt0h, Wt0l, Wt1h, Wt1l, Wt2h, Wt2l,
                                    slab, Nn, Nn * 32);
    k_edges<<<eb8, 256, 0, stream>>>(rowI, colI, slab, Ee);

    const int gx = (Nn + 63) / 64;
    const int ab = (Nn + 3) / 4;     // agg64: 4 waves (nodes) per block
    const int SB = 256;              // node-blocks per slice
    const int npb = (Nn + SB - 1) / SB;
    const int ag = SB * 8;           // 2048 blocks: slice = bid&7

    k_gemm_mfma<2, true><<<2 * gx, 256, 0, stream>>>(Ahi, Alo, Wt0h, Wt0l, slab, Tb, Nn);
    k_agg128s<<<ag, 256, 0, stream>>>(Tb, Ahi, Alo, slab, b0, Nn, npb);
    k_gemm_mfma<2, true><<<2 * gx, 256, 0, stream>>>(Ahi, Alo, Wt1h, Wt1l, slab, Tb, Nn);
    k_agg128s<<<ag, 256, 0, stream>>>(Tb, Ahi, Alo, slab, b1, Nn, npb);
    k_gemm_mfma<1, false><<<gx, 256, 0, stream>>>(Ahi, Alo, Wt2h, Wt2l, slab, Tb, Nn);
    k_agg64<<<ab, 256, 0, stream>>>(Tb, (float*)d_out, slab, b2, Nn);
}

// Round 13
// 469.742 us; speedup vs baseline: 2.0385x; 2.0385x over previous
//
#include <hip/hip_runtime.h>

// GCN: 3-layer, N=100000, E=1600000, feat 128->128->128->64, fp32 in/out.
// R12 (resubmit; R12 bench was a GPU-acquisition timeout, no data):
// revert R11's XCD-sliced agg (request-rate-limited: 8x requests at
// 32B/edge vs 256B/edge -> 305us vs 68us; keep >=256B per gathered edge).
// Back to R10 row-major slab gather. New: k_build fuses prep (x/W bf16
// splits, independent streaming) INTO the atomic-bound edge pass (blocks
// [0,512) prep, rest edges) -- edges is 0.2% VALU / 16% HBM so prep hides.
// cnt[] separate from col slab (400KB memset). dis computed inline.
// 8 dispatches: memset, build, [gemm, agg] x3.

typedef __attribute__((ext_vector_type(8))) short bf16x8;
typedef __attribute__((ext_vector_type(4))) float floatx4;

#define SLOTS 96   // col slots per row
#define PB 512     // prep blocks inside k_build

// ---------------- helpers ----------------

__device__ inline unsigned short f2bf(float f) {
    union { float f; unsigned u; } v; v.f = f;
    unsigned r = v.u + 0x7fffu + ((v.u >> 16) & 1u);  // RNE
    return (unsigned short)(r >> 16);
}

__device__ inline float bf2f(unsigned short h) {
    union { unsigned u; float f; } v; v.u = (unsigned)h << 16;
    return v.f;
}

__device__ inline void split_bf(float v, unsigned short& h, unsigned short& l) {
    h = f2bf(v);
    l = f2bf(v - bf2f(h));
}

__device__ inline void bf2x_to_f(unsigned u, float& a, float& b) {
    union { unsigned x; float f; } lo, hi;
    lo.x = u << 16; hi.x = u & 0xffff0000u;
    a = lo.f; b = hi.f;
}

__device__ inline void accw8(float* acc, uint4 u, float w) {
    float a, b;
    bf2x_to_f(u.x, a, b); acc[0] = fmaf(w, a, acc[0]); acc[1] = fmaf(w, b, acc[1]);
    bf2x_to_f(u.y, a, b); acc[2] = fmaf(w, a, acc[2]); acc[3] = fmaf(w, b, acc[3]);
    bf2x_to_f(u.z, a, b); acc[4] = fmaf(w, a, acc[4]); acc[5] = fmaf(w, b, acc[5]);
    bf2x_to_f(u.w, a, b); acc[6] = fmaf(w, a, acc[6]); acc[7] = fmaf(w, b, acc[7]);
}

// ---------------- fused build: prep blocks + edge-atomic blocks ----------------

__global__ __launch_bounds__(256) void k_build(
    const int* __restrict__ row, const int* __restrict__ col,
    int* __restrict__ cnt, int* __restrict__ slab,
    const float* __restrict__ X,
    unsigned short* __restrict__ Xhi, unsigned short* __restrict__ Xlo,
    const float* __restrict__ W0, const float* __restrict__ W1,
    const float* __restrict__ W2,
    unsigned short* __restrict__ Wt0h, unsigned short* __restrict__ Wt0l,
    unsigned short* __restrict__ Wt1h, unsigned short* __restrict__ Wt1l,
    unsigned short* __restrict__ Wt2h, unsigned short* __restrict__ Wt2l,
    int e, int total4) {
    const int tid = threadIdx.x;
    if (blockIdx.x < PB) {
        // ---- prep: x split + W transposes (streaming, hides under edges)
        int gid = blockIdx.x * 256 + tid;
        const int gsz = PB * 256;
        for (int id = gid; id < total4; id += gsz) {
            float4 v = ((const float4*)X)[id];
            ushort4 h, l;
            split_bf(v.x, h.x, l.x);
            split_bf(v.y, h.y, l.y);
            split_bf(v.z, h.z, l.z);
            split_bf(v.w, h.w, l.w);
            ((ushort4*)Xhi)[id] = h;
            ((ushort4*)Xlo)[id] = l;
        }
        for (int id = gid; id < 128 * 128; id += gsz) {
            int k = id >> 7, nn = id & 127;
            unsigned short h, l;
            split_bf(W0[id], h, l);
            Wt0h[nn * 128 + k] = h;
            Wt0l[nn * 128 + k] = l;
            split_bf(W1[id], h, l);
            Wt1h[nn * 128 + k] = h;
            Wt1l[nn * 128 + k] = l;
        }
        for (int id = gid; id < 128 * 64; id += gsz) {
            int k = id >> 6, nn = id & 63;
            unsigned short h, l;
            split_bf(W2[id], h, l);
            Wt2h[nn * 128 + k] = h;
            Wt2l[nn * 128 + k] = l;
        }
    } else {
        // ---- edges: one atomic pass, 8 edges/thread
        int base = ((blockIdx.x - PB) * 256 + tid) * 8;
        if (base + 7 < e) {
            int4 r0 = *(const int4*)&row[base];
            int4 r1 = *(const int4*)&row[base + 4];
            int4 c0 = *(const int4*)&col[base];
            int4 c1 = *(const int4*)&col[base + 4];
            int s0 = atomicAdd(&cnt[r0.x], 1);
            int s1 = atomicAdd(&cnt[r0.y], 1);
            int s2 = atomicAdd(&cnt[r0.z], 1);
            int s3 = atomicAdd(&cnt[r0.w], 1);
            int s4 = atomicAdd(&cnt[r1.x], 1);
            int s5 = atomicAdd(&cnt[r1.y], 1);
            int s6 = atomicAdd(&cnt[r1.z], 1);
            int s7 = atomicAdd(&cnt[r1.w], 1);
            if (s0 < SLOTS) slab[(size_t)r0.x * SLOTS + s0] = c0.x;
            if (s1 < SLOTS) slab[(size_t)r0.y * SLOTS + s1] = c0.y;
            if (s2 < SLOTS) slab[(size_t)r0.z * SLOTS + s2] = c0.z;
            if (s3 < SLOTS) slab[(size_t)r0.w * SLOTS + s3] = c0.w;
            if (s4 < SLOTS) slab[(size_t)r1.x * SLOTS + s4] = c1.x;
            if (s5 < SLOTS) slab[(size_t)r1.y * SLOTS + s5] = c1.y;
            if (s6 < SLOTS) slab[(size_t)r1.z * SLOTS + s6] = c1.z;
            if (s7 < SLOTS) slab[(size_t)r1.w * SLOTS + s7] = c1.w;
        } else {
            for (int k = base; k < e; k++) {
                int r = row[k];
                int s = atomicAdd(&cnt[r], 1);
                if (s < SLOTS) slab[(size_t)r * SLOTS + s] = col[k];
            }
        }
    }
}

// ---------------- split-bf16 MFMA GEMM, epilogue scales by dis ----------------
// T'[r] = rsqrt(cnt[r]+1) * ((Ah+Al) @ W)[r], bf16 out, row-major.
// Verified layouts: mfma_f32_16x16x32_bf16, A[m=lane&15][k=quad*8+j],
// C/D col=lane&15 row=quad*4+reg.

template <int NB>  // LDW = NB*64
__global__ __launch_bounds__(256) void k_gemm_mfma(
    const unsigned short* __restrict__ Ahi, const unsigned short* __restrict__ Alo,
    const unsigned short* __restrict__ Wthi, const unsigned short* __restrict__ Wtlo,
    const int* __restrict__ cnt, unsigned short* __restrict__ T, int n) {
    const int LDW = NB * 64;
    __shared__ unsigned short Ah_s[64 * 128];
    __shared__ unsigned short Al_s[64 * 128];
    const int tid = threadIdx.x;
    const int bid = blockIdx.x;
    const int bx = (NB == 2) ? (bid >> 1) : bid;
    const int by = (NB == 2) ? (bid & 1) : 0;
    const int row0 = bx * 64;
    const int col0 = by * 64;

    const int wave = tid >> 6, lane = tid & 63;
    const int ln = lane & 15, quad = lane >> 4;
    const int m0 = (wave >> 1) * 32;
    const int nq0 = (wave & 1) * 32;

    bf16x8 Bh[4][2], Bl[4][2];
#pragma unroll
    for (int s = 0; s < 4; s++)
#pragma unroll
        for (int j = 0; j < 2; j++) {
            int ncol = col0 + nq0 + 16 * j + ln;
            int koff = 32 * s + quad * 8;
            Bh[s][j] = *(const bf16x8*)&Wthi[ncol * 128 + koff];
            Bl[s][j] = *(const bf16x8*)&Wtlo[ncol * 128 + koff];
        }

#pragma unroll
    for (int k = 0; k < 4; k++) {
        int id = k * 256 + tid;
        int r = id >> 4, c = id & 15;
        int gr = row0 + r;
        uint4 vh = make_uint4(0, 0, 0, 0), vl = make_uint4(0, 0, 0, 0);
        if (gr < n) {
            vh = *(const uint4*)&Ahi[(size_t)gr * 128 + c * 8];
            vl = *(const uint4*)&Alo[(size_t)gr * 128 + c * 8];
        }
        int pc = c ^ (r & 15);
        *(uint4*)&Ah_s[r * 128 + pc * 8] = vh;
        *(uint4*)&Al_s[r * 128 + pc * 8] = vl;
    }
    __syncthreads();

    floatx4 acc[2][2];
#pragma unroll
    for (int i = 0; i < 2; i++)
#pragma unroll
        for (int j = 0; j < 2; j++) acc[i][j] = (floatx4){0.f, 0.f, 0.f, 0.f};

#pragma unroll
    for (int s = 0; s < 4; s++) {
        bf16x8 ah[2], al[2];
#pragma unroll
        for (int i = 0; i < 2; i++) {
            int off = (m0 + 16 * i + ln) * 128 + ((4 * s + quad) ^ ln) * 8;
            ah[i] = *(const bf16x8*)&Ah_s[off];
            al[i] = *(const bf16x8*)&Al_s[off];
        }
#pragma unroll
        for (int i = 0; i < 2; i++)
#pragma unroll
            for (int j = 0; j < 2; j++) {
                acc[i][j] = __builtin_amdgcn_mfma_f32_16x16x32_bf16(
                    ah[i], Bh[s][j], acc[i][j], 0, 0, 0);
                acc[i][j] = __builtin_amdgcn_mfma_f32_16x16x32_bf16(
                    ah[i], Bl[s][j], acc[i][j], 0, 0, 0);
                acc[i][j] = __builtin_amdgcn_mfma_f32_16x16x32_bf16(
                    al[i], Bh[s][j], acc[i][j], 0, 0, 0);
            }
    }

#pragma unroll
    for (int i = 0; i < 2; i++)
#pragma unroll
        for (int reg = 0; reg < 4; reg++) {
            int gr = row0 + m0 + 16 * i + quad * 4 + reg;
            if (gr < n) {
                float ds = rsqrtf((float)(cnt[gr] + 1));
#pragma unroll
                for (int j = 0; j < 2; j++) {
                    int gc = col0 + nq0 + 16 * j + ln;
                    T[(size_t)gr * LDW + gc] = f2bf(ds * acc[i][j][reg]);
                }
            }
        }
}

// ---------------- aggregation (bf16 T' in, slab cols) ----------------
// Each quad (16 lanes x 16B = 256B/edge) owns a contiguous span of
// ceil(deg/4) edges; unroll x4 with clamped+masked loads -> 4 gathers in
// flight every iteration. out = dis*(sum T'[col] + T'[wid]) + bias.

__global__ void k_agg128(const unsigned short* __restrict__ T,
                         unsigned short* __restrict__ Ohi,
                         unsigned short* __restrict__ Olo,
                         const int* __restrict__ cnt, const int* __restrict__ slab,
                         const float* __restrict__ bias, int n) {
    int wid = (blockIdx.x * blockDim.x + threadIdx.x) >> 6;
    int lane = threadIdx.x & 63;
    if (wid >= n) return;
    const int quad = lane >> 4;
    const int fl = (lane & 15) * 8;
    int degt = cnt[wid];
    int deg = (degt > SLOTS) ? SLOTS : degt;
    int beg = wid * SLOTS;
    int end = beg + deg;
    int span = (deg + 3) >> 2;
    int qb = beg + quad * span;
    int qe = qb + span;
    if (qe > end) qe = end;

    float acc[8] = {0.f, 0.f, 0.f, 0.f, 0.f, 0.f, 0.f, 0.f};
    for (int e = qb; e < qe; e += 4) {
        int l = qe - 1;
        int i1 = e + 1, i2 = e + 2, i3 = e + 3;
        int c0 = slab[e];
        int c1 = slab[i1 < l ? i1 : l];
        int c2 = slab[i2 < l ? i2 : l];
        int c3 = slab[i3 < l ? i3 : l];
        float m1 = (i1 < qe) ? 1.f : 0.f;
        float m2 = (i2 < qe) ? 1.f : 0.f;
        float m3 = (i3 < qe) ? 1.f : 0.f;
        uint4 u0 = *(const uint4*)&T[(size_t)c0 * 128 + fl];
        uint4 u1 = *(const uint4*)&T[(size_t)c1 * 128 + fl];
        uint4 u2 = *(const uint4*)&T[(size_t)c2 * 128 + fl];
        uint4 u3 = *(const uint4*)&T[(size_t)c3 * 128 + fl];
        accw8(acc, u0, 1.f);
        accw8(acc, u1, m1);
        accw8(acc, u2, m2);
        accw8(acc, u3, m3);
    }
#pragma unroll
    for (int k = 0; k < 8; k++) {
        acc[k] += __shfl_xor(acc[k], 16);
        acc[k] += __shfl_xor(acc[k], 32);
    }
    if (quad == 0) {
        uint4 us = *(const uint4*)&T[(size_t)wid * 128 + fl];
        accw8(acc, us, 1.f);  // self term (already dis-scaled)
        float di = rsqrtf((float)(degt + 1));
        float4 bA = *(const float4*)&bias[fl];
        float4 bB = *(const float4*)&bias[fl + 4];
        float bb[8] = {bA.x, bA.y, bA.z, bA.w, bB.x, bB.y, bB.z, bB.w};
        unsigned short h[8], l[8];
#pragma unroll
        for (int k = 0; k < 8; k++) {
            float o = fmaf(di, acc[k], bb[k]);
            o = fmaxf(o, 0.f);  // relu (both 128-wide layers)
            split_bf(o, h[k], l[k]);
        }
        ushort4 h0 = {h[0], h[1], h[2], h[3]}, h1 = {h[4], h[5], h[6], h[7]};
        ushort4 l0 = {l[0], l[1], l[2], l[3]}, l1 = {l[4], l[5], l[6], l[7]};
        *(ushort4*)&Ohi[(size_t)wid * 128 + fl] = h0;
        *(ushort4*)&Ohi[(size_t)wid * 128 + fl + 4] = h1;
        *(ushort4*)&Olo[(size_t)wid * 128 + fl] = l0;
        *(ushort4*)&Olo[(size_t)wid * 128 + fl + 4] = l1;
    }
}

__global__ void k_agg64(const unsigned short* __restrict__ T, float* __restrict__ O,
                        const int* __restrict__ cnt, const int* __restrict__ slab,
                        const float* __restrict__ bias, int n) {
    int wid = (blockIdx.x * blockDim.x + threadIdx.x) >> 6;
    int lane = threadIdx.x & 63;
    if (wid >= n) return;
    const int oct = lane >> 3;
    const int fl = (lane & 7) * 8;
    int degt = cnt[wid];
    int deg = (degt > SLOTS) ? SLOTS : degt;
    int beg = wid * SLOTS;
    int end = beg + deg;
    int span = (deg + 7) >> 3;
    int qb = beg + oct * span;
    int qe = qb + span;
    if (qe > end) qe = end;

    float acc[8] = {0.f, 0.f, 0.f, 0.f, 0.f, 0.f, 0.f, 0.f};
    for (int e = qb; e < qe; e += 4) {
        int l = qe - 1;
        int i1 = e + 1, i2 = e + 2, i3 = e + 3;
        int c0 = slab[e];
        int c1 = slab[i1 < l ? i1 : l];
        int c2 = slab[i2 < l ? i2 : l];
        int c3 = slab[i3 < l ? i3 : l];
        float m1 = (i1 < qe) ? 1.f : 0.f;
        float m2 = (i2 < qe) ? 1.f : 0.f;
        float m3 = (i3 < qe) ? 1.f : 0.f;
        uint4 u0 = *(const uint4*)&T[(size_t)c0 * 64 + fl];
        uint4 u1 = *(const uint4*)&T[(size_t)c1 * 64 + fl];
        uint4 u2 = *(const uint4*)&T[(size_t)c2 * 64 + fl];
        uint4 u3 = *(const uint4*)&T[(size_t)c3 * 64 + fl];
        accw8(acc, u0, 1.f);
        accw8(acc, u1, m1);
        accw8(acc, u2, m2);
        accw8(acc, u3, m3);
    }
#pragma unroll
    for (int k = 0; k < 8; k++) {
        acc[k] += __shfl_xor(acc[k], 8);
        acc[k] += __shfl_xor(acc[k], 16);
        acc[k] += __shfl_xor(acc[k], 32);
    }
    if (oct == 0) {
        uint4 us = *(const uint4*)&T[(size_t)wid * 64 + fl];
        accw8(acc, us, 1.f);  // self term
        float di = rsqrtf((float)(degt + 1));
        float4 bA = *(const float4*)&bias[fl];
        float4 bB = *(const float4*)&bias[fl + 4];
        float bb[8] = {bA.x, bA.y, bA.z, bA.w, bB.x, bB.y, bB.z, bB.w};
        float o[8];
#pragma unroll
        for (int k = 0; k < 8; k++)
            o[k] = fmaf(di, acc[k], bb[k]);
        *(float4*)&O[(size_t)wid * 64 + fl] = make_float4(o[0], o[1], o[2], o[3]);
        *(float4*)&O[(size_t)wid * 64 + fl + 4] = make_float4(o[4], o[5], o[6], o[7]);
    }
}

// ---------------- launch ----------------

static inline char* align256(char* p) {
    return (char*)(((uintptr_t)p + 255) & ~(uintptr_t)255);
}

extern "C" void kernel_launch(void* const* d_in, const int* in_sizes, int n_in,
                              void* d_out, int out_size, void* d_ws, size_t ws_size,
                              hipStream_t stream) {
    const float* x  = (const float*)d_in[0];
    const int*   ei = (const int*)d_in[1];
    const float* W0 = (const float*)d_in[2];
    const float* b0 = (const float*)d_in[3];
    const float* W1 = (const float*)d_in[4];
    const float* b1 = (const float*)d_in[5];
    const float* W2 = (const float*)d_in[6];
    const float* b2 = (const float*)d_in[7];

    const int Nn = in_sizes[0] / 128;
    const int Ee = in_sizes[1] / 2;
    const int* rowI = ei;
    const int* colI = ei + Ee;

    char* p = (char*)d_ws;
    unsigned short* Tb  = (unsigned short*)p; p += (size_t)Nn * 128 * 2; p = align256(p);
    unsigned short* Ahi = (unsigned short*)p; p += (size_t)Nn * 128 * 2; p = align256(p);
    unsigned short* Alo = (unsigned short*)p; p += (size_t)Nn * 128 * 2; p = align256(p);
    int* cnt    = (int*)p;   p += (size_t)Nn * 4;         p = align256(p);
    int* slab   = (int*)p;   p += (size_t)Nn * SLOTS * 4; p = align256(p);
    unsigned short* Wt0h = (unsigned short*)p; p += 128 * 128 * 2;
    unsigned short* Wt0l = (unsigned short*)p; p += 128 * 128 * 2;
    unsigned short* Wt1h = (unsigned short*)p; p += 128 * 128 * 2;
    unsigned short* Wt1l = (unsigned short*)p; p += 128 * 128 * 2;
    unsigned short* Wt2h = (unsigned short*)p; p += 64 * 128 * 2;
    unsigned short* Wt2l = (unsigned short*)p; p += 64 * 128 * 2;

    const int eb8 = (Ee / 8 + 255) / 256;  // edge blocks (8 edges/thread)

    hipMemsetAsync(cnt, 0, (size_t)Nn * 4, stream);
    k_build<<<PB + eb8, 256, 0, stream>>>(rowI, colI, cnt, slab, x, Ahi, Alo,
                                          W0, W1, W2, Wt0h, Wt0l, Wt1h, Wt1l,
                                          Wt2h, Wt2l, Ee, Nn * 32);

    const int gx = (Nn + 63) / 64;
    const int ab = (Nn + 3) / 4;  // 4 waves (nodes) per 256-thread block

    k_gemm_mfma<2><<<2 * gx, 256, 0, stream>>>(Ahi, Alo, Wt0h, Wt0l, cnt, Tb, Nn);
    k_agg128<<<ab, 256, 0, stream>>>(Tb, Ahi, Alo, cnt, slab, b0, Nn);
    k_gemm_mfma<2><<<2 * gx, 256, 0, stream>>>(Ahi, Alo, Wt1h, Wt1l, cnt, Tb, Nn);
    k_agg128<<<ab, 256, 0, stream>>>(Tb, Ahi, Alo, cnt, slab, b1, Nn);
    k_gemm_mfma<1><<<gx, 256, 0, stream>>>(Ahi, Alo, Wt2h, Wt2l, cnt, Tb, Nn);
    k_agg64<<<ab, 256, 0, stream>>>(Tb, (float*)d_out, cnt, slab, b2, Nn);
}